// Round 1
// baseline (897.586 us; speedup 1.0000x reference)
//
#include <hip/hip_runtime.h>

#define CUTOFF 5.0f
#define GAMMA 40.96f          // (32/5)^2
#define PI_F 3.14159265358979f

// ---------------------------------------------------------------------------
// Edge phase: 16 threads per edge (one per channel).
//   - thread c==0 computes geometry (rel, dist, env, unit vector u)
//   - all 16 threads cooperatively compute 32 RBF values into LDS
//   - each thread computes w_e[c] = env * sum_k rbf[k]*W_rbf[k,c],
//     then gp(h[src,c], u) * w_e[c] and 8 float atomicAdds into agg[dst,c,:]
//   - edges with env==0 (dist >= cutoff, ~60%) skip gather + atomics entirely
// ---------------------------------------------------------------------------
__global__ __launch_bounds__(256) void edge_scatter(
    const float* __restrict__ h, const float* __restrict__ pos,
    const int* __restrict__ ei, const float* __restrict__ Wrbf,
    float* __restrict__ agg, int E)
{
    __shared__ float s_wr[512];        // W_rbf [32,16]
    __shared__ float s_u[16][3];
    __shared__ float s_env[16];
    __shared__ float s_d[16];
    __shared__ int   s_src[16];
    __shared__ int   s_dst[16];
    __shared__ float s_rbf[16][33];    // +1 pad breaks 4-way bank conflict

    const int t  = threadIdx.x;
    const int el = t >> 4;             // edge slot 0..15
    const int c  = t & 15;             // channel
    const long long e = (long long)blockIdx.x * 16 + el;

    s_wr[t]       = Wrbf[t];
    s_wr[t + 256] = Wrbf[t + 256];

    if (c == 0) {
        float env = 0.0f, d = 1.0f;
        int src = 0, dst = 0;
        if (e < (long long)E) {
            src = ei[e];
            dst = ei[E + e];
            float ax = pos[src*3+0], ay = pos[src*3+1], az = pos[src*3+2];
            float bx = pos[dst*3+0], by = pos[dst*3+1], bz = pos[dst*3+2];
            float dx = bx-ax, dy = by-ay, dz = bz-az;
            d = sqrtf(dx*dx + dy*dy + dz*dz + 1e-12f);
            float inv = 1.0f / d;
            if (d < CUTOFF) env = 0.5f * (__cosf(PI_F * d * (1.0f/CUTOFF)) + 1.0f);
            s_u[el][0] = dx*inv; s_u[el][1] = dy*inv; s_u[el][2] = dz*inv;
        }
        s_env[el] = env; s_d[el] = d; s_src[el] = src; s_dst[el] = dst;
    }
    __syncthreads();

    const float env = s_env[el];
    if (env > 0.0f) {
        const float d = s_d[el];
        float x0 = d - (CUTOFF/31.0f) * (float)c;
        float x1 = d - (CUTOFF/31.0f) * (float)(c + 16);
        s_rbf[el][c]      = __expf(-GAMMA * x0 * x0);
        s_rbf[el][c + 16] = __expf(-GAMMA * x1 * x1);
    }
    __syncthreads();

    if (env > 0.0f) {
        float w = 0.0f;
        #pragma unroll
        for (int k = 0; k < 32; ++k)
            w += s_rbf[el][k] * s_wr[k*16 + c];
        w *= env;

        const int src = s_src[el];
        const int dst = s_dst[el];
        const float4* hp = (const float4*)(h + (((long long)src*16 + c) << 3));
        float4 lo = hp[0], hi = hp[1];
        const float a0=lo.x, a1=lo.y, a2=lo.z, a3=lo.w;
        const float a4=hi.x, a5=hi.y, a6=hi.z, a7=hi.w;
        const float ux = s_u[el][0], uy = s_u[el][1], uz = s_u[el][2];

        // gp(a, u) with u = grade-1 (blades e1,e2,e3); blade order:
        // 0:1 1:e1 2:e2 3:e3 4:e12 5:e13 6:e23 7:e123
        const float m0 = a1*ux + a2*uy + a3*uz;
        const float m1 = a0*ux + a4*uy + a5*uz;
        const float m2 = a0*uy - a4*ux + a6*uz;
        const float m3 = a0*uz - a5*ux - a6*uy;
        const float m4 = a1*uy - a2*ux + a7*uz;
        const float m5 = a1*uz - a3*ux - a7*uy;
        const float m6 = a2*uz - a3*uy + a7*ux;
        const float m7 = a6*ux - a5*uy + a4*uz;

        float* ap = agg + (((long long)dst*16 + c) << 3);
        atomicAdd(ap+0, m0*w);
        atomicAdd(ap+1, m1*w);
        atomicAdd(ap+2, m2*w);
        atomicAdd(ap+3, m3*w);
        atomicAdd(ap+4, m4*w);
        atomicAdd(ap+5, m5*w);
        atomicAdd(ap+6, m6*w);
        atomicAdd(ap+7, m7*w);
    }
}

// ---------------------------------------------------------------------------
// Node phase: 16 nodes per 256-thread block, one thread per (node, out-chan).
//   out[n,o,:] = sum_c agg[n,c,:] * W_out[c,o]
//   q  [n,o,:] = sum_c h  [n,c,:] * W_sgp[c,o]
//   res = out + gp(out, q)   (full 8x8 Cayley product)
// LDS node rows padded to 132 floats so the 4 nodes in a wave hit
// distinct banks (132 % 32 = 4).
// ---------------------------------------------------------------------------
__global__ __launch_bounds__(256) void node_finalize(
    const float* __restrict__ agg, const float* __restrict__ h,
    const float* __restrict__ Wout, const float* __restrict__ Wsgp,
    float* __restrict__ out, int N)
{
    __shared__ float s_agg[16*132];
    __shared__ float s_h[16*132];
    __shared__ float s_Wout[256];
    __shared__ float s_Wsgp[256];

    const int t = threadIdx.x;
    const long long nodeBase = (long long)blockIdx.x * 16;

    s_Wout[t] = Wout[t];
    s_Wsgp[t] = Wsgp[t];

    // 16 nodes * 128 floats = 512 float4 per array, 2 per thread
    for (int idx = t; idx < 512; idx += 256) {
        int n = idx >> 5;            // 32 float4 per node
        int r = idx & 31;
        long long node = nodeBase + n;
        float4 va = make_float4(0,0,0,0), vh = va;
        if (node < N) {
            long long g = node * 128 + (long long)r * 4;
            va = *(const float4*)(agg + g);
            vh = *(const float4*)(h + g);
        }
        *(float4*)(&s_agg[n*132 + r*4]) = va;
        *(float4*)(&s_h  [n*132 + r*4]) = vh;
    }
    __syncthreads();

    const int nl = t >> 4;
    const int o  = t & 15;
    const float* A = &s_agg[nl*132];
    const float* H = &s_h[nl*132];

    float o0=0,o1=0,o2=0,o3=0,o4=0,o5=0,o6=0,o7=0;
    float q0=0,q1=0,q2=0,q3=0,q4=0,q5=0,q6=0,q7=0;
    #pragma unroll
    for (int cc = 0; cc < 16; ++cc) {
        const float wo = s_Wout[cc*16 + o];
        const float ws = s_Wsgp[cc*16 + o];
        const float* a = A + cc*8;
        const float* hh = H + cc*8;
        o0 += a[0]*wo; o1 += a[1]*wo; o2 += a[2]*wo; o3 += a[3]*wo;
        o4 += a[4]*wo; o5 += a[5]*wo; o6 += a[6]*wo; o7 += a[7]*wo;
        q0 += hh[0]*ws; q1 += hh[1]*ws; q2 += hh[2]*ws; q3 += hh[3]*ws;
        q4 += hh[4]*ws; q5 += hh[5]*ws; q6 += hh[6]*ws; q7 += hh[7]*ws;
    }

    // full Cl(3,0) geometric product gp(out, q), then add out
    const float r0 = o0 + (o0*q0 + o1*q1 + o2*q2 + o3*q3 - o4*q4 - o5*q5 - o6*q6 - o7*q7);
    const float r1 = o1 + (o0*q1 + o1*q0 - o2*q4 - o3*q5 + o4*q2 + o5*q3 - o6*q7 - o7*q6);
    const float r2 = o2 + (o0*q2 + o1*q4 + o2*q0 - o3*q6 - o4*q1 + o5*q7 + o6*q3 + o7*q5);
    const float r3 = o3 + (o0*q3 + o1*q5 + o2*q6 + o3*q0 - o4*q7 - o5*q1 - o6*q2 - o7*q4);
    const float r4 = o4 + (o0*q4 + o1*q2 - o2*q1 + o3*q7 + o4*q0 - o5*q6 + o6*q5 + o7*q3);
    const float r5 = o5 + (o0*q5 + o1*q3 - o2*q7 - o3*q1 + o4*q6 + o5*q0 - o6*q4 - o7*q2);
    const float r6 = o6 + (o0*q6 + o1*q7 + o2*q3 - o3*q2 - o4*q5 + o5*q4 + o6*q0 + o7*q1);
    const float r7 = o7 + (o0*q7 + o1*q6 - o2*q5 + o3*q4 + o4*q3 - o5*q2 + o6*q1 + o7*q0);

    const long long n = nodeBase + nl;
    if (n < N) {
        float* op = out + (n*16 + o)*8;
        *(float4*)(op)     = make_float4(r0, r1, r2, r3);
        *(float4*)(op + 4) = make_float4(r4, r5, r6, r7);
    }
}

extern "C" void kernel_launch(void* const* d_in, const int* in_sizes, int n_in,
                              void* d_out, int out_size, void* d_ws, size_t ws_size,
                              hipStream_t stream) {
    const float* h    = (const float*)d_in[0];   // [N,16,8]
    const float* pos  = (const float*)d_in[1];   // [N,3]
    const int*   ei   = (const int*)d_in[2];     // [2,E]
    const float* Wrbf = (const float*)d_in[3];   // [32,16]
    const float* Wout = (const float*)d_in[4];   // [16,16]
    const float* Wsgp = (const float*)d_in[5];   // [16,16]
    float* out = (float*)d_out;

    const int N = in_sizes[0] / 128;
    const int E = in_sizes[2] / 2;

    float* agg = (float*)d_ws;                    // [N,16,8] accumulator
    hipMemsetAsync(agg, 0, (size_t)N * 128 * sizeof(float), stream);

    const int edgeBlocks = (E + 15) / 16;
    edge_scatter<<<edgeBlocks, 256, 0, stream>>>(h, pos, ei, Wrbf, agg, E);

    const int nodeBlocks = (N + 15) / 16;
    node_finalize<<<nodeBlocks, 256, 0, stream>>>(agg, h, Wout, Wsgp, out, N);
}

// Round 3
// 192.756 us; speedup vs baseline: 4.6566x; 4.6566x over previous
//
#include <hip/hip_runtime.h>

#define CUTOFF 5.0f
#define GAMMA 40.96f          // (32/5)^2
#define MU_STEP (5.0f/31.0f)
#define PI_F 3.14159265358979f

// ---------------------------------------------------------------------------
// Atomic-free aggregation via device-built CSR (R1 showed the scatter version
// is atomic-transaction-rate bound: 906 MB WRITE_SIZE = 28.3M atomics x 32B).
// Per-edge record is just `src`; geometry + RBF are recomputed in the gather
// (cheap: ~80 VALU/edge-channel).
// ---------------------------------------------------------------------------

// Pass 1: count active edges per destination node.
__global__ __launch_bounds__(256) void k_count(
    const float* __restrict__ pos, const int* __restrict__ ei,
    int* __restrict__ deg, int E)
{
    int e = blockIdx.x * 256 + threadIdx.x;
    if (e >= E) return;
    int src = ei[e], dst = ei[E + e];
    float dx = pos[dst*3+0] - pos[src*3+0];
    float dy = pos[dst*3+1] - pos[src*3+1];
    float dz = pos[dst*3+2] - pos[src*3+2];
    float d = sqrtf(dx*dx + dy*dy + dz*dz + 1e-12f);
    if (d < CUTOFF) atomicAdd(&deg[dst], 1);
}

// Scan step A: per-block (256-wide) sums of deg.
__global__ __launch_bounds__(256) void k_blocksum(
    const int* __restrict__ deg, int* __restrict__ partial, int N)
{
    __shared__ int s[256];
    int i = blockIdx.x * 256 + threadIdx.x;
    s[threadIdx.x] = (i < N) ? deg[i] : 0;
    __syncthreads();
    for (int off = 128; off > 0; off >>= 1) {
        if (threadIdx.x < off) s[threadIdx.x] += s[threadIdx.x + off];
        __syncthreads();
    }
    if (threadIdx.x == 0) partial[blockIdx.x] = s[0];
}

// Scan step B: single-block exclusive scan over the P block sums.
__global__ __launch_bounds__(256) void k_scan_partials(int* __restrict__ partial, int P)
{
    __shared__ int s[256];
    int run = 0;
    for (int base = 0; base < P; base += 256) {
        int i = base + threadIdx.x;
        int v = (i < P) ? partial[i] : 0;
        s[threadIdx.x] = v;
        __syncthreads();
        for (int off = 1; off < 256; off <<= 1) {
            int t = s[threadIdx.x];
            int a = (threadIdx.x >= off) ? s[threadIdx.x - off] : 0;
            __syncthreads();
            s[threadIdx.x] = t + a;
            __syncthreads();
        }
        if (i < P) partial[i] = run + (s[threadIdx.x] - v);
        run += s[255];
        __syncthreads();
    }
}

// Scan step C: per-element exclusive scan + block offset -> off[] and cursor[].
__global__ __launch_bounds__(256) void k_scan_deg(
    const int* __restrict__ deg, const int* __restrict__ partial,
    int* __restrict__ off, int* __restrict__ cursor, int N)
{
    __shared__ int s[256];
    int i = blockIdx.x * 256 + threadIdx.x;
    int v = (i < N) ? deg[i] : 0;
    s[threadIdx.x] = v;
    __syncthreads();
    for (int o = 1; o < 256; o <<= 1) {
        int t = s[threadIdx.x];
        int a = (threadIdx.x >= o) ? s[threadIdx.x - o] : 0;
        __syncthreads();
        s[threadIdx.x] = t + a;
        __syncthreads();
    }
    int excl = (s[threadIdx.x] - v) + partial[blockIdx.x];
    if (i < N) { off[i] = excl; cursor[i] = excl; }
}

// Pass 2: place src of each active edge into its dst's CSR segment.
// Predicate computation is byte-identical to k_count (same rounding).
__global__ __launch_bounds__(256) void k_fill(
    const float* __restrict__ pos, const int* __restrict__ ei,
    int* __restrict__ cursor, int* __restrict__ rec_src, int E)
{
    int e = blockIdx.x * 256 + threadIdx.x;
    if (e >= E) return;
    int src = ei[e], dst = ei[E + e];
    float dx = pos[dst*3+0] - pos[src*3+0];
    float dy = pos[dst*3+1] - pos[src*3+1];
    float dz = pos[dst*3+2] - pos[src*3+2];
    float d = sqrtf(dx*dx + dy*dy + dz*dz + 1e-12f);
    if (d < CUTOFF) {
        int slot = atomicAdd(&cursor[dst], 1);
        rec_src[slot] = src;
    }
}

// Gather + finalize, fused: 16 nodes/block, thread (nl,c) accumulates its
// node's messages for channel c in registers (no global agg round-trip),
// then LDS channel mix + node geometric product epilogue.
__global__ __launch_bounds__(256) void k_gather_finalize(
    const float* __restrict__ h, const float* __restrict__ pos,
    const int* __restrict__ rec_src, const int* __restrict__ off,
    const int* __restrict__ deg, const float* __restrict__ Wrbf,
    const float* __restrict__ Wout, const float* __restrict__ Wsgp,
    float* __restrict__ out, int N)
{
    __shared__ float s_wr[512];        // W_rbf [32,16]
    __shared__ float s_Wout[256];
    __shared__ float s_Wsgp[256];
    __shared__ float s_agg[16*132];    // stride 132: wave's 4 nodes -> distinct banks
    __shared__ float s_h[16*132];

    const int t  = threadIdx.x;
    const int nl = t >> 4;
    const int c  = t & 15;
    const long long nodeBase = (long long)blockIdx.x * 16;
    const long long n = nodeBase + nl;

    s_wr[t]       = Wrbf[t];
    s_wr[t + 256] = Wrbf[t + 256];
    s_Wout[t] = Wout[t];
    s_Wsgp[t] = Wsgp[t];

    // stage h[node] rows for the q-mix
    for (int idx = t; idx < 512; idx += 256) {
        int nn = idx >> 5;
        int r  = idx & 31;
        long long node = nodeBase + nn;
        float4 vh = make_float4(0,0,0,0);
        if (node < N) vh = *(const float4*)(h + node*128 + (long long)r*4);
        *(float4*)(&s_h[nn*132 + r*4]) = vh;
    }

    // register accumulation of messages for (n, c)
    float m0=0,m1=0,m2=0,m3=0,m4=0,m5=0,m6=0,m7=0;
    if (n < N) {
        const float px = pos[n*3+0], py = pos[n*3+1], pz = pos[n*3+2];
        const int start = off[n];
        const int dg    = deg[n];
        for (int i = 0; i < dg; ++i) {
            const int src = rec_src[start + i];
            const float dx = px - pos[src*3+0];
            const float dy = py - pos[src*3+1];
            const float dz = pz - pos[src*3+2];
            const float d = sqrtf(dx*dx + dy*dy + dz*dz + 1e-12f);
            const float inv = 1.0f / d;
            const float ux = dx*inv, uy = dy*inv, uz = dz*inv;
            const float env = 0.5f * (__cosf(PI_F * d * (1.0f/CUTOFF)) + 1.0f);

            // w_e[c] = env * sum_k exp(-gamma (d - mu_k)^2) * Wrbf[k,c]
            float w = 0.0f;
            #pragma unroll
            for (int k = 0; k < 32; ++k) {
                float x = d - MU_STEP * (float)k;
                w += __expf(-GAMMA * x * x) * s_wr[k*16 + c];
            }
            w *= env;

            const float4* hp = (const float4*)(h + (((long long)src*16 + c) << 3));
            float4 lo = hp[0], hi = hp[1];
            const float a0=lo.x, a1=lo.y, a2=lo.z, a3=lo.w;
            const float a4=hi.x, a5=hi.y, a6=hi.z, a7=hi.w;

            // gp(a, u), u grade-1; blades: 0:1 1:e1 2:e2 3:e3 4:e12 5:e13 6:e23 7:e123
            m0 += (a1*ux + a2*uy + a3*uz) * w;
            m1 += (a0*ux + a4*uy + a5*uz) * w;
            m2 += (a0*uy - a4*ux + a6*uz) * w;
            m3 += (a0*uz - a5*ux - a6*uy) * w;
            m4 += (a1*uy - a2*ux + a7*uz) * w;
            m5 += (a1*uz - a3*ux - a7*uy) * w;
            m6 += (a2*uz - a3*uy + a7*ux) * w;
            m7 += (a6*ux - a5*uy + a4*uz) * w;
        }
    }

    __syncthreads();   // covers the s_h staging too
    float* ag = &s_agg[nl*132 + c*8];
    ag[0]=m0; ag[1]=m1; ag[2]=m2; ag[3]=m3; ag[4]=m4; ag[5]=m5; ag[6]=m6; ag[7]=m7;
    __syncthreads();

    const int o = c;
    const float* A = &s_agg[nl*132];
    const float* H = &s_h[nl*132];

    float o0=0,o1=0,o2=0,o3=0,o4=0,o5=0,o6=0,o7=0;
    float q0=0,q1=0,q2=0,q3=0,q4=0,q5=0,q6=0,q7=0;
    #pragma unroll
    for (int cc = 0; cc < 16; ++cc) {
        const float wo = s_Wout[cc*16 + o];
        const float ws = s_Wsgp[cc*16 + o];
        const float* a  = A + cc*8;
        const float* hh = H + cc*8;
        o0 += a[0]*wo; o1 += a[1]*wo; o2 += a[2]*wo; o3 += a[3]*wo;
        o4 += a[4]*wo; o5 += a[5]*wo; o6 += a[6]*wo; o7 += a[7]*wo;
        q0 += hh[0]*ws; q1 += hh[1]*ws; q2 += hh[2]*ws; q3 += hh[3]*ws;
        q4 += hh[4]*ws; q5 += hh[5]*ws; q6 += hh[6]*ws; q7 += hh[7]*ws;
    }

    // res = out + gp(out, q), full Cl(3,0) Cayley product
    const float r0 = o0 + (o0*q0 + o1*q1 + o2*q2 + o3*q3 - o4*q4 - o5*q5 - o6*q6 - o7*q7);
    const float r1 = o1 + (o0*q1 + o1*q0 - o2*q4 - o3*q5 + o4*q2 + o5*q3 - o6*q7 - o7*q6);
    const float r2 = o2 + (o0*q2 + o1*q4 + o2*q0 - o3*q6 - o4*q1 + o5*q7 + o6*q3 + o7*q5);
    const float r3 = o3 + (o0*q3 + o1*q5 + o2*q6 + o3*q0 - o4*q7 - o5*q1 - o6*q2 - o7*q4);
    const float r4 = o4 + (o0*q4 + o1*q2 - o2*q1 + o3*q7 + o4*q0 - o5*q6 + o6*q5 + o7*q3);
    const float r5 = o5 + (o0*q5 + o1*q3 - o2*q7 - o3*q1 + o4*q6 + o5*q0 - o6*q4 - o7*q2);
    const float r6 = o6 + (o0*q6 + o1*q7 + o2*q3 - o3*q2 - o4*q5 + o5*q4 + o6*q0 + o7*q1);
    const float r7 = o7 + (o0*q7 + o1*q6 - o2*q5 + o3*q4 + o4*q3 - o5*q2 + o6*q1 + o7*q0);

    if (n < N) {
        float* op = out + (n*16 + o)*8;
        *(float4*)(op)     = make_float4(r0, r1, r2, r3);
        *(float4*)(op + 4) = make_float4(r4, r5, r6, r7);
    }
}

extern "C" void kernel_launch(void* const* d_in, const int* in_sizes, int n_in,
                              void* d_out, int out_size, void* d_ws, size_t ws_size,
                              hipStream_t stream) {
    const float* h    = (const float*)d_in[0];   // [N,16,8]
    const float* pos  = (const float*)d_in[1];   // [N,3]
    const int*   ei   = (const int*)d_in[2];     // [2,E]
    const float* Wrbf = (const float*)d_in[3];   // [32,16]
    const float* Wout = (const float*)d_in[4];   // [16,16]
    const float* Wsgp = (const float*)d_in[5];   // [16,16]
    float* out = (float*)d_out;

    const int N = in_sizes[0] / 128;
    const int E = in_sizes[2] / 2;

    const int nBlocks = (N + 255) / 256;   // scan blocks (196 for N=50k)
    int* deg     = (int*)d_ws;             // [N]
    int* off     = deg + N;                // [N]
    int* cursor  = off + N;                // [N]
    int* partial = cursor + N;             // [nBlocks]
    int* rec_src = partial + ((nBlocks + 63) & ~63);  // [<=E]

    hipMemsetAsync(deg, 0, (size_t)N * sizeof(int), stream);

    const int eBlocks = (E + 255) / 256;
    k_count<<<eBlocks, 256, 0, stream>>>(pos, ei, deg, E);
    k_blocksum<<<nBlocks, 256, 0, stream>>>(deg, partial, N);
    k_scan_partials<<<1, 256, 0, stream>>>(partial, nBlocks);
    k_scan_deg<<<nBlocks, 256, 0, stream>>>(deg, partial, off, cursor, N);
    k_fill<<<eBlocks, 256, 0, stream>>>(pos, ei, cursor, rec_src, E);

    const int gBlocks = (N + 15) / 16;
    k_gather_finalize<<<gBlocks, 256, 0, stream>>>(
        h, pos, rec_src, off, deg, Wrbf, Wout, Wsgp, out, N);
}

// Round 7
// 182.306 us; speedup vs baseline: 4.9235x; 1.0573x over previous
//
#include <hip/hip_runtime.h>

#define CUTOFF 5.0f
#define GAMMA 40.96f              // (32/5)^2
#define MU_STEP 0.16129032f       // 5/31
#define INV_MU 6.2f               // 31/5
#define PI_F 3.14159265358979f

// ---------------------------------------------------------------------------
// CSR-based atomic-free aggregation (R1: scatter was atomic-transaction-rate
// bound; R3: this structure passed at 193 us, gather 87 us VALU-bound 65%).
// R7 = R3's proven gather structure + ONE perf change: RBF truncated to 7
// terms (exp(-1.066 m^2) < 4e-8 beyond |m|=3), plus staging barrier fix and
// merged 1-kernel CSR alloc. Wave-per-node rebalance deferred (single-change
// discipline after 3 infra-failed rounds).
// ---------------------------------------------------------------------------

// Pass 1: per-dst active-edge count + per-edge predicate byte.
__global__ __launch_bounds__(256) void k_count(
    const float* __restrict__ pos, const int* __restrict__ ei,
    int* __restrict__ deg, unsigned char* __restrict__ flags, int E)
{
    int e = blockIdx.x * 256 + threadIdx.x;
    if (e >= E) return;
    int src = ei[e], dst = ei[E + e];
    float dx = pos[dst*3+0] - pos[src*3+0];
    float dy = pos[dst*3+1] - pos[src*3+1];
    float dz = pos[dst*3+2] - pos[src*3+2];
    float d = sqrtf(dx*dx + dy*dy + dz*dz + 1e-12f);
    bool act = d < CUTOFF;
    flags[e] = act ? 1 : 0;
    if (act) atomicAdd(&deg[dst], 1);
}

// CSR segment allocation: block-level inclusive scan + one global bump per
// block. Segment ORDER across nodes is irrelevant for the gather.
__global__ __launch_bounds__(256) void k_alloc(
    const int* __restrict__ deg, int* __restrict__ off_,
    int* __restrict__ cursor, int* __restrict__ counter, int N)
{
    __shared__ int s[256];
    __shared__ int s_base;
    int i = blockIdx.x * 256 + threadIdx.x;
    int v = (i < N) ? deg[i] : 0;
    s[threadIdx.x] = v;
    __syncthreads();
    for (int o = 1; o < 256; o <<= 1) {
        int t = s[threadIdx.x];
        int a = (threadIdx.x >= o) ? s[threadIdx.x - o] : 0;
        __syncthreads();
        s[threadIdx.x] = t + a;
        __syncthreads();
    }
    if (threadIdx.x == 255) s_base = atomicAdd(counter, s[255]);
    __syncthreads();
    int excl = s_base + s[threadIdx.x] - v;
    if (i < N) { off_[i] = excl; cursor[i] = excl; }
}

// Pass 2: drop src of each active edge into its dst's CSR segment.
__global__ __launch_bounds__(256) void k_fill(
    const int* __restrict__ ei, const unsigned char* __restrict__ flags,
    int* __restrict__ cursor, int* __restrict__ rec_src, int E)
{
    int e = blockIdx.x * 256 + threadIdx.x;
    if (e >= E) return;
    if (flags[e]) {
        int slot = atomicAdd(&cursor[ei[E + e]], 1);
        rec_src[slot] = ei[e];
    }
}

// Gather + finalize (R3-proven structure): 16 nodes/block, thread (nl,c)
// accumulates its node's messages for channel c in registers, then LDS
// channel mix + node geometric product epilogue.
__global__ __launch_bounds__(256) void k_gather_finalize(
    const float* __restrict__ h, const float* __restrict__ pos,
    const int* __restrict__ rec_src, const int* __restrict__ off_,
    const int* __restrict__ deg, const float* __restrict__ Wrbf,
    const float* __restrict__ Wout, const float* __restrict__ Wsgp,
    float* __restrict__ out, int N)
{
    __shared__ float s_wr[512];        // W_rbf [32,16]
    __shared__ float s_Wout[256];
    __shared__ float s_Wsgp[256];
    __shared__ float s_agg[16*132];    // stride 132: wave's 4 nodes -> distinct banks
    __shared__ float s_h[16*132];

    const int t  = threadIdx.x;
    const int nl = t >> 4;
    const int c  = t & 15;
    const long long nodeBase = (long long)blockIdx.x * 16;
    const long long n = nodeBase + nl;

    s_wr[t]       = Wrbf[t];
    s_wr[t + 256] = Wrbf[t + 256];
    s_Wout[t] = Wout[t];
    s_Wsgp[t] = Wsgp[t];

    // stage h[node] rows for the q-mix
    for (int idx = t; idx < 512; idx += 256) {
        int nn = idx >> 5;
        int r  = idx & 31;
        long long node = nodeBase + nn;
        float4 vh = make_float4(0,0,0,0);
        if (node < N) vh = *(const float4*)(h + node*128 + (long long)r*4);
        *(float4*)(&s_h[nn*132 + r*4]) = vh;
    }
    __syncthreads();   // s_wr staged by other waves must be visible before reads

    // register accumulation of messages for (n, c)
    float m0=0,m1=0,m2=0,m3=0,m4=0,m5=0,m6=0,m7=0;
    if (n < N) {
        const float px = pos[n*3+0], py = pos[n*3+1], pz = pos[n*3+2];
        const int start = off_[n];
        const int dg    = deg[n];
        for (int i = 0; i < dg; ++i) {
            const int src = rec_src[start + i];
            const float dx = px - pos[src*3+0];
            const float dy = py - pos[src*3+1];
            const float dz = pz - pos[src*3+2];
            const float d = sqrtf(dx*dx + dy*dy + dz*dz + 1e-12f);
            const float inv = 1.0f / d;
            const float ux = dx*inv, uy = dy*inv, uz = dz*inv;
            const float env = 0.5f * (__cosf(PI_F * d * (1.0f/CUTOFF)) + 1.0f);

            // truncated RBF: only |k - round(d/mu)| <= 3 contribute > 4e-8
            const int k0 = __float2int_rn(d * INV_MU);
            const int kl = max(0, k0 - 3);
            const int kh = min(31, k0 + 3);
            float w = 0.0f;
            for (int k = kl; k <= kh; ++k) {
                const float x = d - MU_STEP * (float)k;
                w += __expf(-GAMMA * x * x) * s_wr[k*16 + c];
            }
            w *= env;

            const float4* hp = (const float4*)(h + (((long long)src*16 + c) << 3));
            float4 lo = hp[0], hi = hp[1];
            const float a0=lo.x, a1=lo.y, a2=lo.z, a3=lo.w;
            const float a4=hi.x, a5=hi.y, a6=hi.z, a7=hi.w;

            // gp(a, u), u grade-1; blades: 0:1 1:e1 2:e2 3:e3 4:e12 5:e13 6:e23 7:e123
            m0 += (a1*ux + a2*uy + a3*uz) * w;
            m1 += (a0*ux + a4*uy + a5*uz) * w;
            m2 += (a0*uy - a4*ux + a6*uz) * w;
            m3 += (a0*uz - a5*ux - a6*uy) * w;
            m4 += (a1*uy - a2*ux + a7*uz) * w;
            m5 += (a1*uz - a3*ux - a7*uy) * w;
            m6 += (a2*uz - a3*uy + a7*ux) * w;
            m7 += (a6*ux - a5*uy + a4*uz) * w;
        }
    }

    __syncthreads();
    float* ag = &s_agg[nl*132 + c*8];
    ag[0]=m0; ag[1]=m1; ag[2]=m2; ag[3]=m3; ag[4]=m4; ag[5]=m5; ag[6]=m6; ag[7]=m7;
    __syncthreads();

    const int o = c;
    const float* A = &s_agg[nl*132];
    const float* H = &s_h[nl*132];

    float o0=0,o1=0,o2=0,o3=0,o4=0,o5=0,o6=0,o7=0;
    float q0=0,q1=0,q2=0,q3=0,q4=0,q5=0,q6=0,q7=0;
    #pragma unroll
    for (int cc = 0; cc < 16; ++cc) {
        const float wo = s_Wout[cc*16 + o];
        const float ws = s_Wsgp[cc*16 + o];
        const float* a  = A + cc*8;
        const float* hh = H + cc*8;
        o0 += a[0]*wo; o1 += a[1]*wo; o2 += a[2]*wo; o3 += a[3]*wo;
        o4 += a[4]*wo; o5 += a[5]*wo; o6 += a[6]*wo; o7 += a[7]*wo;
        q0 += hh[0]*ws; q1 += hh[1]*ws; q2 += hh[2]*ws; q3 += hh[3]*ws;
        q4 += hh[4]*ws; q5 += hh[5]*ws; q6 += hh[6]*ws; q7 += hh[7]*ws;
    }

    // res = out + gp(out, q), full Cl(3,0) Cayley product
    const float r0 = o0 + (o0*q0 + o1*q1 + o2*q2 + o3*q3 - o4*q4 - o5*q5 - o6*q6 - o7*q7);
    const float r1 = o1 + (o0*q1 + o1*q0 - o2*q4 - o3*q5 + o4*q2 + o5*q3 - o6*q7 - o7*q6);
    const float r2 = o2 + (o0*q2 + o1*q4 + o2*q0 - o3*q6 - o4*q1 + o5*q7 + o6*q3 + o7*q5);
    const float r3 = o3 + (o0*q3 + o1*q5 + o2*q6 + o3*q0 - o4*q7 - o5*q1 - o6*q2 - o7*q4);
    const float r4 = o4 + (o0*q4 + o1*q2 - o2*q1 + o3*q7 + o4*q0 - o5*q6 + o6*q5 + o7*q3);
    const float r5 = o5 + (o0*q5 + o1*q3 - o2*q7 - o3*q1 + o4*q6 + o5*q0 - o6*q4 - o7*q2);
    const float r6 = o6 + (o0*q6 + o1*q7 + o2*q3 - o3*q2 - o4*q5 + o5*q4 + o6*q0 + o7*q1);
    const float r7 = o7 + (o0*q7 + o1*q6 - o2*q5 + o3*q4 + o4*q3 - o5*q2 + o6*q1 + o7*q0);

    if (n < N) {
        float* op = out + (n*16 + o)*8;
        *(float4*)(op)     = make_float4(r0, r1, r2, r3);
        *(float4*)(op + 4) = make_float4(r4, r5, r6, r7);
    }
}

extern "C" void kernel_launch(void* const* d_in, const int* in_sizes, int n_in,
                              void* d_out, int out_size, void* d_ws, size_t ws_size,
                              hipStream_t stream) {
    const float* h    = (const float*)d_in[0];   // [N,16,8]
    const float* pos  = (const float*)d_in[1];   // [N,3]
    const int*   ei   = (const int*)d_in[2];     // [2,E]
    const float* Wrbf = (const float*)d_in[3];   // [32,16]
    const float* Wout = (const float*)d_in[4];   // [16,16]
    const float* Wsgp = (const float*)d_in[5];   // [16,16]
    float* out = (float*)d_out;

    const int N = in_sizes[0] / 128;
    const int E = in_sizes[2] / 2;

    // ws layout (ints): deg[N] | counter[64] | off[N] | cursor[N] | rec_src[E] | flags[E bytes]
    int* deg     = (int*)d_ws;
    int* counter = deg + N;
    int* off_    = counter + 64;
    int* cursor  = off_ + N;
    int* rec_src = cursor + N;
    unsigned char* flags = (unsigned char*)(rec_src + E);

    hipMemsetAsync(deg, 0, (size_t)(N + 64) * sizeof(int), stream);  // deg + counter

    const int eBlocks = (E + 255) / 256;
    const int nBlocks = (N + 255) / 256;
    k_count<<<eBlocks, 256, 0, stream>>>(pos, ei, deg, flags, E);
    k_alloc<<<nBlocks, 256, 0, stream>>>(deg, off_, cursor, counter, N);
    k_fill<<<eBlocks, 256, 0, stream>>>(ei, flags, cursor, rec_src, E);

    const int gBlocks = (N + 15) / 16;
    k_gather_finalize<<<gBlocks, 256, 0, stream>>>(
        h, pos, rec_src, off_, deg, Wrbf, Wout, Wsgp, out, N);
}

// Round 8
// 165.003 us; speedup vs baseline: 5.4398x; 1.1049x over previous
//
#include <hip/hip_runtime.h>

#define CUTOFF 5.0f
#define GAMMA 40.96f              // (32/5)^2
#define MU_STEP 0.16129032f       // 5/31
#define INV_MU 6.2f               // 31/5
#define PI_F 3.14159265358979f

// ---------------------------------------------------------------------------
// CSR atomic-free aggregation. R7 measured: gather 74 us, VALUBusy 48%,
// HBM 15% -> mixed VALU + load-latency bound. R8: (a) cooperative RBF --
// one exp per lane covers a 2-edge pair (7x fewer transcendentals), 7-term
// window clamped to [kl, kl+6] subset of [0,31] so no masking; (b) degree
// loop unrolled x2 with hoisted loads (2 independent chains -> MLP x2).
// ---------------------------------------------------------------------------

// Pass 1: per-dst active-edge count + per-edge predicate byte.
__global__ __launch_bounds__(256) void k_count(
    const float* __restrict__ pos, const int* __restrict__ ei,
    int* __restrict__ deg, unsigned char* __restrict__ flags, int E)
{
    int e = blockIdx.x * 256 + threadIdx.x;
    if (e >= E) return;
    int src = ei[e], dst = ei[E + e];
    float dx = pos[dst*3+0] - pos[src*3+0];
    float dy = pos[dst*3+1] - pos[src*3+1];
    float dz = pos[dst*3+2] - pos[src*3+2];
    float d = sqrtf(dx*dx + dy*dy + dz*dz + 1e-12f);
    bool act = d < CUTOFF;
    flags[e] = act ? 1 : 0;
    if (act) atomicAdd(&deg[dst], 1);
}

// CSR segment allocation: block-level inclusive scan + one global bump per
// block. Segment ORDER across nodes is irrelevant for the gather.
__global__ __launch_bounds__(256) void k_alloc(
    const int* __restrict__ deg, int* __restrict__ off_,
    int* __restrict__ cursor, int* __restrict__ counter, int N)
{
    __shared__ int s[256];
    __shared__ int s_base;
    int i = blockIdx.x * 256 + threadIdx.x;
    int v = (i < N) ? deg[i] : 0;
    s[threadIdx.x] = v;
    __syncthreads();
    for (int o = 1; o < 256; o <<= 1) {
        int t = s[threadIdx.x];
        int a = (threadIdx.x >= o) ? s[threadIdx.x - o] : 0;
        __syncthreads();
        s[threadIdx.x] = t + a;
        __syncthreads();
    }
    if (threadIdx.x == 255) s_base = atomicAdd(counter, s[255]);
    __syncthreads();
    int excl = s_base + s[threadIdx.x] - v;
    if (i < N) { off_[i] = excl; cursor[i] = excl; }
}

// Pass 2: drop src of each active edge into its dst's CSR segment.
__global__ __launch_bounds__(256) void k_fill(
    const int* __restrict__ ei, const unsigned char* __restrict__ flags,
    int* __restrict__ cursor, int* __restrict__ rec_src, int E)
{
    int e = blockIdx.x * 256 + threadIdx.x;
    if (e >= E) return;
    if (flags[e]) {
        int slot = atomicAdd(&cursor[ei[E + e]], 1);
        rec_src[slot] = ei[e];
    }
}

// Gather + finalize: 16 nodes/block, thread (nl,c) accumulates channel c of
// node nl. Degree loop processes 2 edges/iter; the 16 lanes of a channel
// group cooperatively compute the pair's 14 RBF exps (1 per lane).
__global__ __launch_bounds__(256) void k_gather_finalize(
    const float* __restrict__ h, const float* __restrict__ pos,
    const int* __restrict__ rec_src, const int* __restrict__ off_,
    const int* __restrict__ deg, const float* __restrict__ Wrbf,
    const float* __restrict__ Wout, const float* __restrict__ Wsgp,
    float* __restrict__ out, int N)
{
    __shared__ float s_wr[512];        // W_rbf [32,16]
    __shared__ float s_Wout[256];
    __shared__ float s_Wsgp[256];
    __shared__ float s_agg[16*132];
    __shared__ float s_h[16*132];

    const int t  = threadIdx.x;
    const int nl = t >> 4;
    const int c  = t & 15;
    const int lane  = t & 63;
    const int gbase = lane & 48;       // channel-group base within wave
    const long long nodeBase = (long long)blockIdx.x * 16;
    const long long n = nodeBase + nl;

    s_wr[t]       = Wrbf[t];
    s_wr[t + 256] = Wrbf[t + 256];
    s_Wout[t] = Wout[t];
    s_Wsgp[t] = Wsgp[t];

    for (int idx = t; idx < 512; idx += 256) {
        int nn = idx >> 5;
        int r  = idx & 31;
        long long node = nodeBase + nn;
        float4 vh = make_float4(0,0,0,0);
        if (node < N) vh = *(const float4*)(h + node*128 + (long long)r*4);
        *(float4*)(&s_h[nn*132 + r*4]) = vh;
    }
    __syncthreads();

    float m0=0,m1=0,m2=0,m3=0,m4=0,m5=0,m6=0,m7=0;
    if (n < N) {
        const float px = pos[n*3+0], py = pos[n*3+1], pz = pos[n*3+2];
        const int start = off_[n];
        const int dg    = deg[n];
        for (int base = 0; base < dg; base += 2) {
            const int i1ok = (base + 1 < dg) ? 1 : 0;
            const int s0 = rec_src[start + base];
            const int s1 = rec_src[start + base + i1ok];   // repeats s0 when odd tail

            // hoist h loads: 2 independent 32B chains in flight during the math
            const float4* hp0 = (const float4*)(h + (((long long)s0*16 + c) << 3));
            const float4* hp1 = (const float4*)(h + (((long long)s1*16 + c) << 3));
            const float4 A0 = hp0[0], B0 = hp0[1];
            const float4 A1 = hp1[0], B1 = hp1[1];

            const float dx0 = px - pos[s0*3+0];
            const float dy0 = py - pos[s0*3+1];
            const float dz0 = pz - pos[s0*3+2];
            const float dx1 = px - pos[s1*3+0];
            const float dy1 = py - pos[s1*3+1];
            const float dz1 = pz - pos[s1*3+2];

            const float d0 = sqrtf(dx0*dx0 + dy0*dy0 + dz0*dz0 + 1e-12f);
            const float d1 = sqrtf(dx1*dx1 + dy1*dy1 + dz1*dz1 + 1e-12f);
            const float inv0 = 1.0f / d0, inv1 = 1.0f / d1;
            const float ux0 = dx0*inv0, uy0 = dy0*inv0, uz0 = dz0*inv0;
            const float ux1 = dx1*inv1, uy1 = dy1*inv1, uz1 = dz1*inv1;
            const float env0 = 0.5f * (__cosf(PI_F * d0 * (1.0f/CUTOFF)) + 1.0f);
            const float env1 = 0.5f * (__cosf(PI_F * d1 * (1.0f/CUTOFF)) + 1.0f);

            // 7-term RBF window, clamped so kl+6 <= 31 (terms outside
            // [k0-3,k0+3] that slip in are < 4e-8 relative -- harmless).
            const int kl0 = min(max(0, __float2int_rn(d0 * INV_MU) - 3), 25);
            const int kl1 = min(max(0, __float2int_rn(d1 * INV_MU) - 3), 25);

            // cooperative exp: lanes 0-7 of the group cover edge0's window,
            // lanes 8-15 cover edge1's (8th lane of each half unused).
            const int   sel   = c >> 3;
            const float dsel  = sel ? d1 : d0;
            const int   klsel = sel ? kl1 : kl0;
            const float xx = dsel - MU_STEP * (float)(klsel + (c & 7));
            const float ee = __expf(-GAMMA * xx * xx);

            float w0 = 0.0f, w1 = 0.0f;
            #pragma unroll
            for (int j = 0; j < 7; ++j) {
                const float e0 = __shfl(ee, gbase + j);
                const float e1 = __shfl(ee, gbase + 8 + j);
                w0 += e0 * s_wr[(kl0 + j)*16 + c];
                w1 += e1 * s_wr[(kl1 + j)*16 + c];
            }
            w0 *= env0;
            w1 *= env1 * (float)i1ok;

            // gp(a, u), u grade-1; blades: 0:1 1:e1 2:e2 3:e3 4:e12 5:e13 6:e23 7:e123
            m0 += (A0.y*ux0 + A0.z*uy0 + A0.w*uz0) * w0 + (A1.y*ux1 + A1.z*uy1 + A1.w*uz1) * w1;
            m1 += (A0.x*ux0 + B0.x*uy0 + B0.y*uz0) * w0 + (A1.x*ux1 + B1.x*uy1 + B1.y*uz1) * w1;
            m2 += (A0.x*uy0 - B0.x*ux0 + B0.z*uz0) * w0 + (A1.x*uy1 - B1.x*ux1 + B1.z*uz1) * w1;
            m3 += (A0.x*uz0 - B0.y*ux0 - B0.z*uy0) * w0 + (A1.x*uz1 - B1.y*ux1 - B1.z*uy1) * w1;
            m4 += (A0.y*uy0 - A0.z*ux0 + B0.w*uz0) * w0 + (A1.y*uy1 - A1.z*ux1 + B1.w*uz1) * w1;
            m5 += (A0.y*uz0 - A0.w*ux0 - B0.w*uy0) * w0 + (A1.y*uz1 - A1.w*ux1 - B1.w*uy1) * w1;
            m6 += (A0.z*uz0 - A0.w*uy0 + B0.w*ux0) * w0 + (A1.z*uz1 - A1.w*uy1 + B1.w*ux1) * w1;
            m7 += (B0.z*ux0 - B0.y*uy0 + B0.x*uz0) * w0 + (B1.z*ux1 - B1.y*uy1 + B1.x*uz1) * w1;
        }
    }

    __syncthreads();
    float* ag = &s_agg[nl*132 + c*8];
    *(float4*)(ag)     = make_float4(m0, m1, m2, m3);
    *(float4*)(ag + 4) = make_float4(m4, m5, m6, m7);
    __syncthreads();

    const int o = c;
    const float* A = &s_agg[nl*132];
    const float* H = &s_h[nl*132];

    float o0=0,o1=0,o2=0,o3=0,o4=0,o5=0,o6=0,o7=0;
    float q0=0,q1=0,q2=0,q3=0,q4=0,q5=0,q6=0,q7=0;
    #pragma unroll
    for (int cc = 0; cc < 16; ++cc) {
        const float wo = s_Wout[cc*16 + o];
        const float ws = s_Wsgp[cc*16 + o];
        const float* a  = A + cc*8;
        const float* hh = H + cc*8;
        o0 += a[0]*wo; o1 += a[1]*wo; o2 += a[2]*wo; o3 += a[3]*wo;
        o4 += a[4]*wo; o5 += a[5]*wo; o6 += a[6]*wo; o7 += a[7]*wo;
        q0 += hh[0]*ws; q1 += hh[1]*ws; q2 += hh[2]*ws; q3 += hh[3]*ws;
        q4 += hh[4]*ws; q5 += hh[5]*ws; q6 += hh[6]*ws; q7 += hh[7]*ws;
    }

    // res = out + gp(out, q), full Cl(3,0) Cayley product
    const float r0 = o0 + (o0*q0 + o1*q1 + o2*q2 + o3*q3 - o4*q4 - o5*q5 - o6*q6 - o7*q7);
    const float r1 = o1 + (o0*q1 + o1*q0 - o2*q4 - o3*q5 + o4*q2 + o5*q3 - o6*q7 - o7*q6);
    const float r2 = o2 + (o0*q2 + o1*q4 + o2*q0 - o3*q6 - o4*q1 + o5*q7 + o6*q3 + o7*q5);
    const float r3 = o3 + (o0*q3 + o1*q5 + o2*q6 + o3*q0 - o4*q7 - o5*q1 - o6*q2 - o7*q4);
    const float r4 = o4 + (o0*q4 + o1*q2 - o2*q1 + o3*q7 + o4*q0 - o5*q6 + o6*q5 + o7*q3);
    const float r5 = o5 + (o0*q5 + o1*q3 - o2*q7 - o3*q1 + o4*q6 + o5*q0 - o6*q4 - o7*q2);
    const float r6 = o6 + (o0*q6 + o1*q7 + o2*q3 - o3*q2 - o4*q5 + o5*q4 + o6*q0 + o7*q1);
    const float r7 = o7 + (o0*q7 + o1*q6 - o2*q5 + o3*q4 + o4*q3 - o5*q2 + o6*q1 + o7*q0);

    if (n < N) {
        float* op = out + (n*16 + o)*8;
        *(float4*)(op)     = make_float4(r0, r1, r2, r3);
        *(float4*)(op + 4) = make_float4(r4, r5, r6, r7);
    }
}

extern "C" void kernel_launch(void* const* d_in, const int* in_sizes, int n_in,
                              void* d_out, int out_size, void* d_ws, size_t ws_size,
                              hipStream_t stream) {
    const float* h    = (const float*)d_in[0];   // [N,16,8]
    const float* pos  = (const float*)d_in[1];   // [N,3]
    const int*   ei   = (const int*)d_in[2];     // [2,E]
    const float* Wrbf = (const float*)d_in[3];   // [32,16]
    const float* Wout = (const float*)d_in[4];   // [16,16]
    const float* Wsgp = (const float*)d_in[5];   // [16,16]
    float* out = (float*)d_out;

    const int N = in_sizes[0] / 128;
    const int E = in_sizes[2] / 2;

    // ws layout (ints): deg[N] | counter[64] | off[N] | cursor[N] | rec_src[E] | flags[E bytes]
    int* deg     = (int*)d_ws;
    int* counter = deg + N;
    int* off_    = counter + 64;
    int* cursor  = off_ + N;
    int* rec_src = cursor + N;
    unsigned char* flags = (unsigned char*)(rec_src + E);

    hipMemsetAsync(deg, 0, (size_t)(N + 64) * sizeof(int), stream);  // deg + counter

    const int eBlocks = (E + 255) / 256;
    const int nBlocks = (N + 255) / 256;
    k_count<<<eBlocks, 256, 0, stream>>>(pos, ei, deg, flags, E);
    k_alloc<<<nBlocks, 256, 0, stream>>>(deg, off_, cursor, counter, N);
    k_fill<<<eBlocks, 256, 0, stream>>>(ei, flags, cursor, rec_src, E);

    const int gBlocks = (N + 15) / 16;
    k_gather_finalize<<<gBlocks, 256, 0, stream>>>(
        h, pos, rec_src, off_, deg, Wrbf, Wout, Wsgp, out, N);
}

// Round 9
// 149.247 us; speedup vs baseline: 6.0141x; 1.1056x over previous
//
#include <hip/hip_runtime.h>

#define CUTOFF 5.0f
#define GAMMA 40.96f              // (32/5)^2
#define MU_STEP 0.16129032f       // 5/31
#define INV_MU 6.2f               // 31/5
#define PI_F 3.14159265358979f
#define MAXDEG 64                 // Poisson(4.42): P(deg>=25) ~ 1e-12; 64 = huge margin

// ---------------------------------------------------------------------------
// R9: one-pass CSR via fixed-stride buckets. R8 ledger: gather 63.8 us but
// ~101 us in memset+count+alloc+fill+6 dispatch overheads (~10 us each).
// rec[dst*64 + atomicAdd(deg[dst],1)] = src removes count/scan/fill pipeline,
// one full ei pass, and 3 dispatches (6 -> 3). Gather phase = R8 verbatim,
// reading fixed-stride buckets.
// ---------------------------------------------------------------------------

__global__ __launch_bounds__(256) void k_fill_direct(
    const float* __restrict__ pos, const int* __restrict__ ei,
    int* __restrict__ deg, int* __restrict__ rec, int E)
{
    int e = blockIdx.x * 256 + threadIdx.x;
    if (e >= E) return;
    int src = ei[e], dst = ei[E + e];
    float dx = pos[dst*3+0] - pos[src*3+0];
    float dy = pos[dst*3+1] - pos[src*3+1];
    float dz = pos[dst*3+2] - pos[src*3+2];
    float d = sqrtf(dx*dx + dy*dy + dz*dz + 1e-12f);
    if (d < CUTOFF) {
        int slot = atomicAdd(&deg[dst], 1);
        if (slot < MAXDEG) rec[dst*MAXDEG + slot] = src;   // guard: never taken in practice
    }
}

// Gather + finalize: 16 nodes/block, thread (nl,c) accumulates channel c of
// node nl. Degree loop processes 2 edges/iter; the 16 lanes of a channel
// group cooperatively compute the pair's 14 RBF exps (1 per lane).
__global__ __launch_bounds__(256) void k_gather_finalize(
    const float* __restrict__ h, const float* __restrict__ pos,
    const int* __restrict__ rec, const int* __restrict__ deg,
    const float* __restrict__ Wrbf, const float* __restrict__ Wout,
    const float* __restrict__ Wsgp, float* __restrict__ out, int N)
{
    __shared__ float s_wr[512];        // W_rbf [32,16]
    __shared__ float s_Wout[256];
    __shared__ float s_Wsgp[256];
    __shared__ float s_agg[16*132];
    __shared__ float s_h[16*132];

    const int t  = threadIdx.x;
    const int nl = t >> 4;
    const int c  = t & 15;
    const int lane  = t & 63;
    const int gbase = lane & 48;       // channel-group base within wave
    const long long nodeBase = (long long)blockIdx.x * 16;
    const long long n = nodeBase + nl;

    s_wr[t]       = Wrbf[t];
    s_wr[t + 256] = Wrbf[t + 256];
    s_Wout[t] = Wout[t];
    s_Wsgp[t] = Wsgp[t];

    for (int idx = t; idx < 512; idx += 256) {
        int nn = idx >> 5;
        int r  = idx & 31;
        long long node = nodeBase + nn;
        float4 vh = make_float4(0,0,0,0);
        if (node < N) vh = *(const float4*)(h + node*128 + (long long)r*4);
        *(float4*)(&s_h[nn*132 + r*4]) = vh;
    }
    __syncthreads();

    float m0=0,m1=0,m2=0,m3=0,m4=0,m5=0,m6=0,m7=0;
    if (n < N) {
        const float px = pos[n*3+0], py = pos[n*3+1], pz = pos[n*3+2];
        const int start = (int)n * MAXDEG;
        const int dg    = min(deg[n], MAXDEG);
        for (int base = 0; base < dg; base += 2) {
            const int i1ok = (base + 1 < dg) ? 1 : 0;
            const int s0 = rec[start + base];
            const int s1 = rec[start + base + i1ok];   // repeats s0 when odd tail

            // hoist h loads: 2 independent 32B chains in flight during the math
            const float4* hp0 = (const float4*)(h + (((long long)s0*16 + c) << 3));
            const float4* hp1 = (const float4*)(h + (((long long)s1*16 + c) << 3));
            const float4 A0 = hp0[0], B0 = hp0[1];
            const float4 A1 = hp1[0], B1 = hp1[1];

            const float dx0 = px - pos[s0*3+0];
            const float dy0 = py - pos[s0*3+1];
            const float dz0 = pz - pos[s0*3+2];
            const float dx1 = px - pos[s1*3+0];
            const float dy1 = py - pos[s1*3+1];
            const float dz1 = pz - pos[s1*3+2];

            const float d0 = sqrtf(dx0*dx0 + dy0*dy0 + dz0*dz0 + 1e-12f);
            const float d1 = sqrtf(dx1*dx1 + dy1*dy1 + dz1*dz1 + 1e-12f);
            const float inv0 = 1.0f / d0, inv1 = 1.0f / d1;
            const float ux0 = dx0*inv0, uy0 = dy0*inv0, uz0 = dz0*inv0;
            const float ux1 = dx1*inv1, uy1 = dy1*inv1, uz1 = dz1*inv1;
            const float env0 = 0.5f * (__cosf(PI_F * d0 * (1.0f/CUTOFF)) + 1.0f);
            const float env1 = 0.5f * (__cosf(PI_F * d1 * (1.0f/CUTOFF)) + 1.0f);

            // 7-term RBF window, clamped so kl+6 <= 31 (terms outside
            // [k0-3,k0+3] that slip in are < 4e-8 relative -- harmless).
            const int kl0 = min(max(0, __float2int_rn(d0 * INV_MU) - 3), 25);
            const int kl1 = min(max(0, __float2int_rn(d1 * INV_MU) - 3), 25);

            // cooperative exp: lanes 0-7 of the group cover edge0's window,
            // lanes 8-15 cover edge1's (8th lane of each half unused).
            const int   sel   = c >> 3;
            const float dsel  = sel ? d1 : d0;
            const int   klsel = sel ? kl1 : kl0;
            const float xx = dsel - MU_STEP * (float)(klsel + (c & 7));
            const float ee = __expf(-GAMMA * xx * xx);

            float w0 = 0.0f, w1 = 0.0f;
            #pragma unroll
            for (int j = 0; j < 7; ++j) {
                const float e0 = __shfl(ee, gbase + j);
                const float e1 = __shfl(ee, gbase + 8 + j);
                w0 += e0 * s_wr[(kl0 + j)*16 + c];
                w1 += e1 * s_wr[(kl1 + j)*16 + c];
            }
            w0 *= env0;
            w1 *= env1 * (float)i1ok;

            // gp(a, u), u grade-1; blades: 0:1 1:e1 2:e2 3:e3 4:e12 5:e13 6:e23 7:e123
            m0 += (A0.y*ux0 + A0.z*uy0 + A0.w*uz0) * w0 + (A1.y*ux1 + A1.z*uy1 + A1.w*uz1) * w1;
            m1 += (A0.x*ux0 + B0.x*uy0 + B0.y*uz0) * w0 + (A1.x*ux1 + B1.x*uy1 + B1.y*uz1) * w1;
            m2 += (A0.x*uy0 - B0.x*ux0 + B0.z*uz0) * w0 + (A1.x*uy1 - B1.x*ux1 + B1.z*uz1) * w1;
            m3 += (A0.x*uz0 - B0.y*ux0 - B0.z*uy0) * w0 + (A1.x*uz1 - B1.y*ux1 - B1.z*uy1) * w1;
            m4 += (A0.y*uy0 - A0.z*ux0 + B0.w*uz0) * w0 + (A1.y*uy1 - A1.z*ux1 + B1.w*uz1) * w1;
            m5 += (A0.y*uz0 - A0.w*ux0 - B0.w*uy0) * w0 + (A1.y*uz1 - A1.w*ux1 - B1.w*uy1) * w1;
            m6 += (A0.z*uz0 - A0.w*uy0 + B0.w*ux0) * w0 + (A1.z*uz1 - A1.w*uy1 + B1.w*ux1) * w1;
            m7 += (B0.z*ux0 - B0.y*uy0 + B0.x*uz0) * w0 + (B1.z*ux1 - B1.y*uy1 + B1.x*uz1) * w1;
        }
    }

    __syncthreads();
    float* ag = &s_agg[nl*132 + c*8];
    *(float4*)(ag)     = make_float4(m0, m1, m2, m3);
    *(float4*)(ag + 4) = make_float4(m4, m5, m6, m7);
    __syncthreads();

    const int o = c;
    const float* A = &s_agg[nl*132];
    const float* H = &s_h[nl*132];

    float o0=0,o1=0,o2=0,o3=0,o4=0,o5=0,o6=0,o7=0;
    float q0=0,q1=0,q2=0,q3=0,q4=0,q5=0,q6=0,q7=0;
    #pragma unroll
    for (int cc = 0; cc < 16; ++cc) {
        const float wo = s_Wout[cc*16 + o];
        const float ws = s_Wsgp[cc*16 + o];
        const float* a  = A + cc*8;
        const float* hh = H + cc*8;
        o0 += a[0]*wo; o1 += a[1]*wo; o2 += a[2]*wo; o3 += a[3]*wo;
        o4 += a[4]*wo; o5 += a[5]*wo; o6 += a[6]*wo; o7 += a[7]*wo;
        q0 += hh[0]*ws; q1 += hh[1]*ws; q2 += hh[2]*ws; q3 += hh[3]*ws;
        q4 += hh[4]*ws; q5 += hh[5]*ws; q6 += hh[6]*ws; q7 += hh[7]*ws;
    }

    // res = out + gp(out, q), full Cl(3,0) Cayley product
    const float r0 = o0 + (o0*q0 + o1*q1 + o2*q2 + o3*q3 - o4*q4 - o5*q5 - o6*q6 - o7*q7);
    const float r1 = o1 + (o0*q1 + o1*q0 - o2*q4 - o3*q5 + o4*q2 + o5*q3 - o6*q7 - o7*q6);
    const float r2 = o2 + (o0*q2 + o1*q4 + o2*q0 - o3*q6 - o4*q1 + o5*q7 + o6*q3 + o7*q5);
    const float r3 = o3 + (o0*q3 + o1*q5 + o2*q6 + o3*q0 - o4*q7 - o5*q1 - o6*q2 - o7*q4);
    const float r4 = o4 + (o0*q4 + o1*q2 - o2*q1 + o3*q7 + o4*q0 - o5*q6 + o6*q5 + o7*q3);
    const float r5 = o5 + (o0*q5 + o1*q3 - o2*q7 - o3*q1 + o4*q6 + o5*q0 - o6*q4 - o7*q2);
    const float r6 = o6 + (o0*q6 + o1*q7 + o2*q3 - o3*q2 - o4*q5 + o5*q4 + o6*q0 + o7*q1);
    const float r7 = o7 + (o0*q7 + o1*q6 - o2*q5 + o3*q4 + o4*q3 - o5*q2 + o6*q1 + o7*q0);

    if (n < N) {
        float* op = out + (n*16 + o)*8;
        *(float4*)(op)     = make_float4(r0, r1, r2, r3);
        *(float4*)(op + 4) = make_float4(r4, r5, r6, r7);
    }
}

extern "C" void kernel_launch(void* const* d_in, const int* in_sizes, int n_in,
                              void* d_out, int out_size, void* d_ws, size_t ws_size,
                              hipStream_t stream) {
    const float* h    = (const float*)d_in[0];   // [N,16,8]
    const float* pos  = (const float*)d_in[1];   // [N,3]
    const int*   ei   = (const int*)d_in[2];     // [2,E]
    const float* Wrbf = (const float*)d_in[3];   // [32,16]
    const float* Wout = (const float*)d_in[4];   // [16,16]
    const float* Wsgp = (const float*)d_in[5];   // [16,16]
    float* out = (float*)d_out;

    const int N = in_sizes[0] / 128;
    const int E = in_sizes[2] / 2;

    // ws layout (ints): deg[N] | rec[N*MAXDEG]  (~13 MB; harness ws >= 25.6 MB per R1)
    int* deg = (int*)d_ws;
    int* rec = deg + N;

    hipMemsetAsync(deg, 0, (size_t)N * sizeof(int), stream);

    const int eBlocks = (E + 255) / 256;
    k_fill_direct<<<eBlocks, 256, 0, stream>>>(pos, ei, deg, rec, E);

    const int gBlocks = (N + 15) / 16;
    k_gather_finalize<<<gBlocks, 256, 0, stream>>>(
        h, pos, rec, deg, Wrbf, Wout, Wsgp, out, N);
}